// Round 1
// baseline (508.532 us; speedup 1.0000x reference)
//
#include <hip/hip_runtime.h>
#include <hip/hip_bf16.h>

typedef __bf16 bf16x8 __attribute__((ext_vector_type(8)));
typedef float f32x4 __attribute__((ext_vector_type(4)));

#define NB 4
#define NC 256
#define NN 4096
#define BQ 64
#define BK 64

// ---------- prep: x fp32 [b][c][n] -> xt bf16 [b][n][c] (transposed), xc bf16 [b][c][n] ----------
__global__ __launch_bounds__(256) void prep_kernel(const float* __restrict__ x,
                                                   __bf16* __restrict__ xt,
                                                   __bf16* __restrict__ xc) {
    __shared__ __bf16 tile[64][65];  // +1 pad breaks bank conflicts on transpose read
    const int b = blockIdx.z, c0 = blockIdx.y * 64, n0 = blockIdx.x * 64;
    const int t = threadIdx.x;
#pragma unroll
    for (int it = 0; it < 16; ++it) {
        int idx = it * 256 + t;
        int cc = idx >> 6, nn = idx & 63;
        size_t gi = ((size_t)(b * NC + c0 + cc)) * NN + n0 + nn;
        __bf16 bv = (__bf16)x[gi];       // coalesced fp32 read, coalesced bf16 write
        xc[gi] = bv;
        tile[cc][nn] = bv;
    }
    __syncthreads();
#pragma unroll
    for (int it = 0; it < 16; ++it) {
        int idx = it * 256 + t;
        int nn = idx >> 6, cc = idx & 63;
        xt[((size_t)(b * NN + n0 + nn)) * NC + c0 + cc] = tile[cc][nn];  // coalesced over c
    }
}

// XOR swizzles: 8-element (16B) granularity, spreads rows across banks (G4)
__device__ __forceinline__ int swzK(int row, int col) { return row * NC + (col ^ ((row & 7) << 3)); }
__device__ __forceinline__ int swzV(int c, int j)     { return c * BK + (j ^ ((c & 7) << 3)); }
__device__ __forceinline__ int swzP(int i, int j)     { return i * BK + (j ^ ((i & 7) << 3)); }

// ---------- flash attention: one block per (batch, 64-row q-block) ----------
__global__ __launch_bounds__(256) void flash_kernel(const __bf16* __restrict__ xt,
                                                    const __bf16* __restrict__ xc,
                                                    float* __restrict__ out) {
    __shared__ __align__(16) __bf16 sK[BK * NC];    // K tile [64 j][256 c], swizzled
    __shared__ __align__(16) __bf16 sVT[NC * BK];   // V^T tile [256 c][64 j], swizzled
    __shared__ __align__(16) __bf16 sP[4][16 * BK]; // per-wave P strip [16 i][64 j], swizzled

    // XCD-aware decode: batch b -> XCDs {2b, 2b+1} so each XCD's L2 holds one batch's 4MB
    const int bid = blockIdx.x;
    const int x8 = bid & 7;
    const int b = x8 >> 1;
    const int qblk = ((bid >> 3) << 1) | (x8 & 1);

    const int tid = threadIdx.x;
    const int w = tid >> 6;       // wave 0..3, owns 16 q-rows
    const int lane = tid & 63;
    const int l16 = lane & 15;
    const int g = lane >> 4;

    const int i_base = qblk * BQ + w * 16;

    // Q fragments held in registers: A[i][k], i = lane%16, k = (lane/16)*8 + t
    bf16x8 qf[8];
    const __bf16* qrow = xt + ((size_t)(b * NN + i_base + l16)) * NC + g * 8;
#pragma unroll
    for (int ck = 0; ck < 8; ++ck) qf[ck] = *(const bf16x8*)(qrow + ck * 32);

    f32x4 acc[16];  // O strip [16 i][256 c] = 16 col-frags
#pragma unroll
    for (int cf = 0; cf < 16; ++cf) acc[cf] = (f32x4){0.f, 0.f, 0.f, 0.f};
    float m_run[4], l_run[4];
#pragma unroll
    for (int r = 0; r < 4; ++r) { m_run[r] = -1e30f; l_run[r] = 0.f; }

    const __bf16* kbase = xt + ((size_t)b * NN) * NC;
    const __bf16* vbase = xc + ((size_t)b * NC) * NN;

    for (int kb = 0; kb < NN / BK; ++kb) {
        __syncthreads();  // previous tile fully consumed before overwrite
        // stage K tile [64][256]: 2048 16B chunks, coalesced
        const __bf16* ksrc = kbase + (size_t)(kb * BK) * NC;
#pragma unroll
        for (int it = 0; it < 8; ++it) {
            int lidx = it * 256 + tid;
            int row = lidx >> 5;
            int co = (lidx & 31) << 3;
            *(bf16x8*)(&sK[swzK(row, co)]) = *(const bf16x8*)(ksrc + row * NC + co);
        }
        // stage V^T tile [256 c][64 j] straight from original layout
#pragma unroll
        for (int it = 0; it < 8; ++it) {
            int lidx = it * 256 + tid;
            int c = lidx >> 3;
            int j = (lidx & 7) << 3;
            *(bf16x8*)(&sVT[swzV(c, j)]) = *(const bf16x8*)(vbase + (size_t)c * NN + kb * BK + j);
        }
        __syncthreads();

        // S = Q·K^T  (B[k=c][j]: j = lane%16 -> K row jf*16+l16, c-chunk contiguous)
        f32x4 s[4];
#pragma unroll
        for (int jf = 0; jf < 4; ++jf) s[jf] = (f32x4){0.f, 0.f, 0.f, 0.f};
#pragma unroll
        for (int ck = 0; ck < 8; ++ck)
#pragma unroll
            for (int jf = 0; jf < 4; ++jf) {
                bf16x8 kf = *(const bf16x8*)(&sK[swzK(jf * 16 + l16, ck * 32 + g * 8)]);
                s[jf] = __builtin_amdgcn_mfma_f32_16x16x32_bf16(qf[ck], kf, s[jf], 0, 0, 0);
            }

        // online softmax; D layout: col=lane&15, row=(lane>>4)*4+r -> row-reduce over l16
        float scale[4];
#pragma unroll
        for (int r = 0; r < 4; ++r) {
            float v = fmaxf(fmaxf(s[0][r], s[1][r]), fmaxf(s[2][r], s[3][r]));
            v = fmaxf(v, __shfl_xor(v, 1));
            v = fmaxf(v, __shfl_xor(v, 2));
            v = fmaxf(v, __shfl_xor(v, 4));
            v = fmaxf(v, __shfl_xor(v, 8));
            float mn = fmaxf(m_run[r], v);
            scale[r] = __expf(m_run[r] - mn);
            m_run[r] = mn;
        }
#pragma unroll
        for (int jf = 0; jf < 4; ++jf)
#pragma unroll
            for (int r = 0; r < 4; ++r)
                s[jf][r] = __expf(s[jf][r] - m_run[r]);
#pragma unroll
        for (int r = 0; r < 4; ++r) {
            float v = s[0][r] + s[1][r] + s[2][r] + s[3][r];
            v += __shfl_xor(v, 1);
            v += __shfl_xor(v, 2);
            v += __shfl_xor(v, 4);
            v += __shfl_xor(v, 8);
            l_run[r] = l_run[r] * scale[r] + v;
        }
#pragma unroll
        for (int cf = 0; cf < 16; ++cf)
#pragma unroll
            for (int r = 0; r < 4; ++r) acc[cf][r] *= scale[r];

        // P -> LDS (wave-private strip; same-wave DS ops are in-order, no barrier needed)
        __bf16* myP = &sP[w][0];
#pragma unroll
        for (int jf = 0; jf < 4; ++jf)
#pragma unroll
            for (int r = 0; r < 4; ++r)
                myP[swzP(g * 4 + r, jf * 16 + l16)] = (__bf16)s[jf][r];

        // O += P·V   (A[i][j]: i=lane%16, j-chunk contiguous; B[j][c] from sVT rows = c)
#pragma unroll
        for (int jb = 0; jb < 2; ++jb) {
            bf16x8 pa = *(const bf16x8*)(&myP[swzP(l16, jb * 32 + g * 8)]);
#pragma unroll
            for (int cf = 0; cf < 16; ++cf) {
                bf16x8 bv = *(const bf16x8*)(&sVT[swzV(cf * 16 + l16, jb * 32 + g * 8)]);
                acc[cf] = __builtin_amdgcn_mfma_f32_16x16x32_bf16(pa, bv, acc[cf], 0, 0, 0);
            }
        }
    }

    // epilogue: /= l, transpose via LDS (reuse sP[w]), store coalesced along n
    float inv_l[4];
#pragma unroll
    for (int r = 0; r < 4; ++r) inv_l[r] = 1.f / l_run[r];

    float* sT = (float*)&sP[w][0];  // 16*17*4 = 1088B fits in the 2KB wave strip
    __syncthreads();
#pragma unroll
    for (int cf = 0; cf < 16; ++cf) {
#pragma unroll
        for (int r = 0; r < 4; ++r) sT[(g * 4 + r) * 17 + l16] = acc[cf][r] * inv_l[r];
        __syncthreads();
#pragma unroll
        for (int r = 0; r < 4; ++r) {
            int c = cf * 16 + g + r * 4;
            out[((size_t)(b * NC + c)) * NN + i_base + l16] = sT[l16 * 17 + g + r * 4];
        }
        __syncthreads();
    }
}

extern "C" void kernel_launch(void* const* d_in, const int* in_sizes, int n_in,
                              void* d_out, int out_size, void* d_ws, size_t ws_size,
                              hipStream_t stream) {
    const float* x = (const float*)d_in[0];
    float* out = (float*)d_out;
    __bf16* xt = (__bf16*)d_ws;                       // [4][4096][256] bf16 = 8 MiB
    __bf16* xc = xt + (size_t)NB * NN * NC;           // [4][256][4096] bf16 = 8 MiB

    dim3 pgrid(NN / 64, NC / 64, NB);
    prep_kernel<<<pgrid, dim3(256), 0, stream>>>(x, xt, xc);
    flash_kernel<<<dim3(256), dim3(256), 0, stream>>>(xt, xc, out);
}

// Round 3
// 242.191 us; speedup vs baseline: 2.0997x; 2.0997x over previous
//
#include <hip/hip_runtime.h>
#include <hip/hip_bf16.h>

typedef __bf16 bf16x8 __attribute__((ext_vector_type(8)));
typedef float f32x4 __attribute__((ext_vector_type(4)));

#define NB 4
#define NC 256
#define NN 4096
#define BK 32
#define NT 64   // tiles per j-group: 2 groups * 64 tiles * BK = 4096

__device__ __forceinline__ void stage16(const void* g, void* l) {
    __builtin_amdgcn_global_load_lds(
        (const __attribute__((address_space(1))) unsigned int*)g,
        (__attribute__((address_space(3))) unsigned int*)l, 16, 0, 0);
}

// ---------- prep: x fp32 [b][c][n] -> xt bf16 [b][n][c] (transposed), xc bf16 [b][c][n] ----------
__global__ __launch_bounds__(256) void prep_kernel(const float* __restrict__ x,
                                                   __bf16* __restrict__ xt,
                                                   __bf16* __restrict__ xc) {
    __shared__ __align__(16) __bf16 tile[64 * 64];  // swizzled 16B chunks, no pad
    const int b = blockIdx.z, c0 = blockIdx.y * 64, n0 = blockIdx.x * 64;
    const int t = threadIdx.x;
    {
        const int cc = t >> 2, nch = (t & 3) << 4;   // 16 floats per thread
        const float* src = x + ((size_t)(b * NC + c0 + cc)) * NN + n0 + nch;
        f32x4 v[4];
        v[0] = *(const f32x4*)(src);
        v[1] = *(const f32x4*)(src + 4);
        v[2] = *(const f32x4*)(src + 8);
        v[3] = *(const f32x4*)(src + 12);
        bf16x8 o[2];
#pragma unroll
        for (int q = 0; q < 2; ++q)
#pragma unroll
            for (int k = 0; k < 8; ++k)
                o[q][k] = (__bf16)v[q * 2 + (k >> 2)][k & 3];
        __bf16* dst = xc + ((size_t)(b * NC + c0 + cc)) * NN + n0 + nch;
        *(bf16x8*)(dst) = o[0];
        *(bf16x8*)(dst + 8) = o[1];
        const int key = (cc ^ (cc >> 3)) & 7;        // rows 16 apart get distinct keys
#pragma unroll
        for (int q = 0; q < 2; ++q) {
            int nc = (nch >> 3) + q;
            *(bf16x8*)(&tile[cc * 64 + ((nc ^ key) << 3)]) = o[q];
        }
    }
    __syncthreads();
    {
        const int nn = t >> 2, cch = (t & 3) << 4;
        bf16x8 o[2];
#pragma unroll
        for (int k = 0; k < 16; ++k) {
            int r = cch + k;
            int key = (r ^ (r >> 3)) & 7;
            o[k >> 3][k & 7] = tile[r * 64 + (((nn >> 3) ^ key) << 3) + (nn & 7)];
        }
        __bf16* dst = xt + ((size_t)(b * NN + n0 + nn)) * NC + c0 + cch;
        *(bf16x8*)(dst) = o[0];
        *(bf16x8*)(dst + 8) = o[1];
    }
}

// ---------- flash attention: 1 block/CU, 8 waves = 2 KV-groups x 4 q-strips ----------
__global__ __launch_bounds__(512, 2) void flash_kernel(const __bf16* __restrict__ xt,
                                                       const __bf16* __restrict__ xc,
                                                       float* __restrict__ out) {
    __shared__ __align__(16) __bf16 sK[2][2][BK * NC];  // [group][buf][32 j][256 c] 64KB
    __shared__ __align__(16) __bf16 sV[2][2][NC * BK];  // [group][buf][256 c][32 j] 64KB
    __shared__ __align__(16) __bf16 sP[8][16 * BK];     // per-wave P strip, 8KB
    __shared__ float sML[8][16][2];                     // m,l exchange, 1KB

    const int bid = blockIdx.x;
    const int b = (bid & 7) >> 1;                        // batch -> XCD pair
    const int qblk = ((bid >> 3) << 1) | (bid & 1);

    const int tid = threadIdx.x;
    const int w = tid >> 6;
    const int grp = w >> 2;        // 0: tiles 0..63, 1: tiles 64..127
    const int wg = w & 3;          // q-strip
    const int lane = tid & 63;
    const int l16 = lane & 15;
    const int gq = lane >> 4;

    const int i_base = qblk * 64 + wg * 16;

    const char* xtb = (const char*)(xt + (size_t)b * NN * NC);
    const char* xcb = (const char*)(xc + (size_t)b * NC * NN);

    // Q fragments in registers: A[i=l16][k = gq*8+e + 32*ck]
    bf16x8 qf[8];
    {
        const __bf16* qrow = (const __bf16*)xtb + (size_t)(i_base + l16) * NC + gq * 8;
#pragma unroll
        for (int ck = 0; ck < 8; ++ck) qf[ck] = *(const bf16x8*)(qrow + ck * 32);
    }

    f32x4 acc[16];
#pragma unroll
    for (int cf = 0; cf < 16; ++cf) acc[cf] = (f32x4){0.f, 0.f, 0.f, 0.f};
    float m_run[4], l_run[4];
#pragma unroll
    for (int r = 0; r < 4; ++r) { m_run[r] = -3.0e38f; l_run[r] = 0.f; }

    // stage tile t of this wave's group into buffer bf via global_load_lds
    // (linear LDS dest; swizzle applied by permuting the GLOBAL source chunk - rule #21)
    auto stage = [&](int bf, int t) {
        const int tj = grp * NT + t;
        const char* kb = xtb + (size_t)tj * BK * (NC * 2);
        __bf16* dk = &sK[grp][bf][0];
#pragma unroll
        for (int q = 0; q < 4; ++q) {
            int ci = wg * 4 + q;                 // 1KB chunk = 2 K-rows
            int rl = ci * 2 + (lane >> 5);
            int cs = (lane & 31) ^ (rl & 7);     // inverse of read swizzle
            stage16(kb + rl * 512 + cs * 16, dk + ci * 512);
        }
        const char* vb = xcb + (size_t)tj * (BK * 2);
        __bf16* dv = &sV[grp][bf][0];
#pragma unroll
        for (int q = 0; q < 4; ++q) {
            int ci = wg * 4 + q;                 // 1KB chunk = 16 c-rows
            int c = ci * 16 + (lane >> 2);
            int cs = (lane & 3) ^ ((c >> 1) & 3);
            stage16(vb + (size_t)c * (NN * 2) + cs * 16, dv + ci * 512);
        }
    };

    stage(0, 0);
    __syncthreads();
    int cur = 0;

    for (int t = 0; t < NT; ++t) {
        if (t + 1 < NT) stage(cur ^ 1, t + 1);   // issue-early; drains at the barrier below

        const __bf16* kt = &sK[grp][cur][0];
        const __bf16* vt = &sV[grp][cur][0];

        // S = Q K^T  (two 16-col fragments cover BK=32)
        f32x4 s0 = (f32x4){0.f, 0.f, 0.f, 0.f};
        f32x4 s1 = (f32x4){0.f, 0.f, 0.f, 0.f};
#pragma unroll
        for (int ck = 0; ck < 8; ++ck) {
            int q = ck * 4 + gq;
            bf16x8 k0 = *(const bf16x8*)(kt + l16 * 256 + ((q ^ (l16 & 7)) << 3));
            s0 = __builtin_amdgcn_mfma_f32_16x16x32_bf16(qf[ck], k0, s0, 0, 0, 0);
            int row1 = 16 + l16;
            bf16x8 k1 = *(const bf16x8*)(kt + row1 * 256 + ((q ^ (row1 & 7)) << 3));
            s1 = __builtin_amdgcn_mfma_f32_16x16x32_bf16(qf[ck], k1, s1, 0, 0, 0);
        }

        // online softmax; D: row i = gq*4+r, col j = l16 (+16 for s1)
        float vmax[4];
#pragma unroll
        for (int r = 0; r < 4; ++r) {
            float v = fmaxf(s0[r], s1[r]);
            v = fmaxf(v, __shfl_xor(v, 1));
            v = fmaxf(v, __shfl_xor(v, 2));
            v = fmaxf(v, __shfl_xor(v, 4));
            v = fmaxf(v, __shfl_xor(v, 8));
            vmax[r] = v;
        }
        bool grow = (vmax[0] > m_run[0]) || (vmax[1] > m_run[1]) ||
                    (vmax[2] > m_run[2]) || (vmax[3] > m_run[3]);
        if (__any((int)grow)) {                  // exact skip: only rescale when a max grew
#pragma unroll
            for (int r = 0; r < 4; ++r) {
                float nm = fmaxf(m_run[r], vmax[r]);
                float sc = __expf(m_run[r] - nm);
                m_run[r] = nm;
                l_run[r] *= sc;
#pragma unroll
                for (int cf = 0; cf < 16; ++cf) acc[cf][r] *= sc;
            }
        }
        float p0[4], p1[4];
#pragma unroll
        for (int r = 0; r < 4; ++r) {
            p0[r] = __expf(s0[r] - m_run[r]);
            p1[r] = __expf(s1[r] - m_run[r]);
            float v = p0[r] + p1[r];
            v += __shfl_xor(v, 1);
            v += __shfl_xor(v, 2);
            v += __shfl_xor(v, 4);
            v += __shfl_xor(v, 8);
            l_run[r] += v;
        }

        // P -> wave-private LDS strip (swizzled), then read back as A-fragment
        __bf16* myP = &sP[w][0];
#pragma unroll
        for (int r = 0; r < 4; ++r) {
            int i = gq * 4 + r;
            int key = (i >> 1) & 3;
            myP[i * 32 + (((l16 >> 3) ^ key) << 3) + (l16 & 7)] = (__bf16)p0[r];
            int j1 = 16 + l16;
            myP[i * 32 + (((j1 >> 3) ^ key) << 3) + (j1 & 7)] = (__bf16)p1[r];
        }
        bf16x8 pa = *(const bf16x8*)(&myP[l16 * 32 + ((gq ^ ((l16 >> 1) & 3)) << 3)]);

        // O += P V   (B[k=j][n=c_sub] from sV rows c = cf*16+l16)
#pragma unroll
        for (int cf = 0; cf < 16; ++cf) {
            int c = cf * 16 + l16;
            bf16x8 bv = *(const bf16x8*)(vt + c * 32 + ((gq ^ ((c >> 1) & 3)) << 3));
            acc[cf] = __builtin_amdgcn_mfma_f32_16x16x32_bf16(pa, bv, acc[cf], 0, 0, 0);
        }

        __syncthreads();   // all waves done with buf[cur]; next-tile gl_lds drained here
        cur ^= 1;
    }

    // ---- merge the two j-halves (waves w and w+4 share a q-strip) ----
    if (l16 == 0) {
#pragma unroll
        for (int r = 0; r < 4; ++r) {
            sML[w][gq * 4 + r][0] = m_run[r];
            sML[w][gq * 4 + r][1] = l_run[r];
        }
    }
    if (w >= 4) {
        float* F = ((float*)&sK[0][0][0]) + (size_t)(w - 4) * 4096;  // 16KB strip in dead K buffers
#pragma unroll
        for (int cf = 0; cf < 16; ++cf)
#pragma unroll
            for (int r = 0; r < 4; ++r)
                F[cf * 256 + (gq * 4 + r) * 16 + l16] = acc[cf][r];
    }
    __syncthreads();
    if (w < 4) {
        const float* F = ((float*)&sK[0][0][0]) + (size_t)w * 4096;
        float sA[4], sB[4], inv[4];
#pragma unroll
        for (int r = 0; r < 4; ++r) {
            int i = gq * 4 + r;
            float mA = m_run[r], lA = l_run[r];
            float mB = sML[w + 4][i][0], lB = sML[w + 4][i][1];
            float m = fmaxf(mA, mB);
            float eA = __expf(mA - m), eB = __expf(mB - m);
            sA[r] = eA; sB[r] = eB;
            inv[r] = 1.f / (lA * eA + lB * eB);
        }
        // wave-private transpose buffer in the dead V region; stores coalesced along n
        float* sT = (float*)((char*)&sV[0][0][0] + (size_t)w * 4096);
#pragma unroll
        for (int cf = 0; cf < 16; ++cf) {
#pragma unroll
            for (int r = 0; r < 4; ++r) {
                float o = (acc[cf][r] * sA[r] +
                           F[cf * 256 + (gq * 4 + r) * 16 + l16] * sB[r]) * inv[r];
                sT[(gq * 4 + r) * 17 + l16] = o;
            }
#pragma unroll
            for (int r = 0; r < 4; ++r) {
                int c = cf * 16 + gq + r * 4;
                out[((size_t)(b * NC + c)) * NN + i_base + l16] = sT[l16 * 17 + gq + r * 4];
            }
        }
    }
}

extern "C" void kernel_launch(void* const* d_in, const int* in_sizes, int n_in,
                              void* d_out, int out_size, void* d_ws, size_t ws_size,
                              hipStream_t stream) {
    const float* x = (const float*)d_in[0];
    float* out = (float*)d_out;
    __bf16* xt = (__bf16*)d_ws;                       // [4][4096][256] bf16 = 8 MiB
    __bf16* xc = xt + (size_t)NB * NN * NC;           // [4][256][4096] bf16 = 8 MiB

    prep_kernel<<<dim3(NN / 64, NC / 64, NB), dim3(256), 0, stream>>>(x, xt, xc);
    flash_kernel<<<dim3(256), dim3(512), 0, stream>>>(xt, xc, out);
}